// Round 1
// baseline (434.757 us; speedup 1.0000x reference)
//
#include <hip/hip_runtime.h>
#include <stdint.h>

#define DEVINL __device__ __forceinline__

typedef __attribute__((ext_vector_type(8))) __bf16 bf16x8;
typedef __attribute__((ext_vector_type(8))) short s16x8;
typedef __attribute__((ext_vector_type(4))) float f32x4;

constexpr int NN = 5000;   // nodes
constexpr int NE = 10000;  // edges
constexpr int NG = 200;    // graphs
constexpr int BM = 128;
constexpr int MBLK = (NE + BM - 1) / BM;  // 79
constexpr int EROWS = MBLK * BM;          // 10112 (padded rows in U)
constexpr int KSPLIT = 4;

DEVINL short f2bf(float f) {  // RNE fp32->bf16
  union { float f; unsigned u; } v; v.f = f;
  unsigned u = v.u + 0x7fffu + ((v.u >> 16) & 1u);
  return (short)(u >> 16);
}

DEVINL void gload16(const void* g, void* l) {
  __builtin_amdgcn_global_load_lds(
      (const __attribute__((address_space(1))) void*)g,
      (__attribute__((address_space(3))) void*)l, 16, 0, 0);
}

// ---------------- small kernels ----------------

__global__ void count_edges(const int* dst, float* cnt) {
  int e = blockIdx.x * 256 + threadIdx.x;
  if (e < NE) atomicAdd(&cnt[dst[e]], 1.0f);
}

__global__ void count_graphs(const int* batch, float* gcnt) {
  int n = blockIdx.x * 256 + threadIdx.x;
  if (n < NN) atomicAdd(&gcnt[batch[n]], 1.0f);
}

// h = relu(edge_attr @ w1 + b1)   [E,3]@[3,32]
__global__ void edge_mlp(const float* ea, const float* w1, const float* b1, float* h) {
  __shared__ float w1s[96];
  __shared__ float b1s[32];
  int t = threadIdx.x;
  if (t < 96) w1s[t] = w1[t];
  if (t < 32) b1s[t] = b1[t];
  __syncthreads();
  int e = blockIdx.x * 8 + (t >> 5);
  int k = t & 31;
  if (e < NE) {
    float a0 = ea[e * 3 + 0], a1 = ea[e * 3 + 1], a2 = ea[e * 3 + 2];
    float v = b1s[k] + a0 * w1s[k] + a1 * w1s[32 + k] + a2 * w1s[64 + k];
    h[e * 32 + k] = v > 0.f ? v : 0.f;
  }
}

// B panel build: Bp[kt][n][kk] bf16, 16B chunks XOR-swizzled by ((n>>1)&3)
template <int DIN, int DOUT, int KTOT>
__global__ void build_B(const float* w2, const float* b2, short* Bp) {
  int idx = blockIdx.x * 256 + threadIdx.x;
  constexpr int TOTC = (KTOT / 8) * DOUT;
  if (idx >= TOTC) return;
  int cc = idx & 3;
  int n = (idx >> 2) % DOUT;
  int kt = (idx >> 2) / DOUT;
  int kap0 = kt * 32 + cc * 8;
  s16x8 v;
#pragma unroll
  for (int j = 0; j < 8; ++j) {
    int kap = kap0 + j;
    float val = 0.f;
    if (kap < 33 * DIN) {
      int k = kap / DIN, i = kap % DIN;
      val = (k < 32) ? w2[(size_t)(k * DIN + i) * DOUT + n] : b2[(size_t)i * DOUT + n];
    }
    v[j] = f2bf(val);
  }
  int swz = cc ^ ((n >> 1) & 3);
  *(s16x8*)((char*)Bp + (size_t)kt * DOUT * 64 + n * 64 + swz * 16) = v;
}

// U build: U[e, k*DIN+i] = h~[e,k] * x[src[e], i]  (h~[32]=1 folds b2), bf16, swizzled
template <int DIN, int DOUT, int KTOT, bool POW2>
__global__ void build_U(const float* x, const float* h, const int* src, short* U) {
  constexpr int CPE = KTOT / 8;
  int idx = blockIdx.x * 256 + threadIdx.x;
  int e = idx / CPE;
  int c = idx % CPE;
  if (e >= NE) return;
  int kap0 = c * 8;
  const float* xr = x + (size_t)src[e] * DIN;
  s16x8 v;
  if (POW2) {
    int k = kap0 / DIN;           // compile-time shift
    int i0 = kap0 % DIN;
    float hf = (k < 32) ? h[e * 32 + k] : 1.0f;
    float4 xa = *(const float4*)(xr + i0);
    float4 xb = *(const float4*)(xr + i0 + 4);
    v[0] = f2bf(hf * xa.x); v[1] = f2bf(hf * xa.y);
    v[2] = f2bf(hf * xa.z); v[3] = f2bf(hf * xa.w);
    v[4] = f2bf(hf * xb.x); v[5] = f2bf(hf * xb.y);
    v[6] = f2bf(hf * xb.z); v[7] = f2bf(hf * xb.w);
  } else {
#pragma unroll
    for (int j = 0; j < 8; ++j) {
      int kap = kap0 + j;
      float val = 0.f;
      if (kap < 33 * DIN) {
        int k = kap / DIN, i = kap % DIN;
        float hf = (k < 32) ? h[e * 32 + k] : 1.0f;
        val = hf * xr[i];
      }
      v[j] = f2bf(val);
    }
  }
  int kt = c >> 2, cc = c & 3;
  int swz = cc ^ ((e >> 1) & 3);
  *(s16x8*)((char*)U + (size_t)e * (KTOT * 2) + (size_t)kt * 64 + swz * 16) = v;
}

// GEMM msg = U @ B with fused atomic scatter-add into agg[dst[e], :]
template <int DIN, int DOUT, int KTOT>
__launch_bounds__(256, 2)
__global__ void gemm_scatter(const short* U, const short* Bp, const int* dstI, float* agg) {
  constexpr int NT = DOUT / 32;            // 16-col frags per wave (wave covers DOUT/2 cols)
  constexpr int MT = 4;                    // wave covers 64 rows
  constexpr int STEPS = KTOT / 32;
  constexpr int PER = (STEPS + KSPLIT - 1) / KSPLIT;
  constexpr int BCALLS = DOUT / 64;        // 1KB gload calls per wave for B
  __shared__ __align__(16) char Alds[BM * 64];
  __shared__ __align__(16) char Blds[DOUT * 64];
  __shared__ int dst_s[BM];
  const int t = threadIdx.x, lane = t & 63, w = t >> 6;
  const int wm = w >> 1, wn = w & 1;
  const int m0 = blockIdx.x * BM;
  if (t < BM) { int e = m0 + t; dst_s[t] = (e < NE) ? dstI[e] : -1; }
  const int s0 = blockIdx.y * PER;
  const int s1 = (s0 + PER < STEPS) ? (s0 + PER) : STEPS;

  f32x4 acc[MT][NT];
#pragma unroll
  for (int mt = 0; mt < MT; ++mt)
#pragma unroll
    for (int nt = 0; nt < NT; ++nt)
#pragma unroll
      for (int i = 0; i < 4; ++i) acc[mt][nt][i] = 0.f;

  const char* Ug = (const char*)U + (size_t)m0 * (KTOT * 2);
  for (int s = s0; s < s1; ++s) {
    __syncthreads();  // previous iter's LDS reads done before re-staging
    // stage A tile [128 rows][64B] -- linear copy, swizzle pre-baked in U
#pragma unroll
    for (int c = 0; c < 2; ++c) {
      int b = w * 2048 + c * 1024 + lane * 16;
      gload16(Ug + (size_t)(b >> 6) * (KTOT * 2) + (size_t)s * 64 + (b & 63),
              Alds + w * 2048 + c * 1024);
    }
    // stage B panel [DOUT rows][64B]
    const char* Bg = (const char*)Bp + (size_t)s * (DOUT * 64);
#pragma unroll
    for (int c = 0; c < BCALLS; ++c) {
      int off = w * (BCALLS * 1024) + c * 1024;
      gload16(Bg + off + lane * 16, Blds + off);
    }
    __syncthreads();  // implicit vmcnt(0): gload_lds data visible
    bf16x8 bfr[NT];
#pragma unroll
    for (int nt = 0; nt < NT; ++nt) {
      int n = wn * (DOUT / 2) + nt * 16 + (lane & 15);
      int cch = (lane >> 4) ^ ((n >> 1) & 3);
      bfr[nt] = *(const bf16x8*)(Blds + n * 64 + cch * 16);
    }
#pragma unroll
    for (int mt = 0; mt < MT; ++mt) {
      int r = wm * 64 + mt * 16 + (lane & 15);
      int cch = (lane >> 4) ^ ((r >> 1) & 3);
      bf16x8 afr = *(const bf16x8*)(Alds + r * 64 + cch * 16);
#pragma unroll
      for (int nt = 0; nt < NT; ++nt)
        acc[mt][nt] = __builtin_amdgcn_mfma_f32_16x16x32_bf16(afr, bfr[nt], acc[mt][nt], 0, 0, 0);
    }
  }
  __syncthreads();
  // epilogue: C layout col=lane&15, row=(lane>>4)*4+reg (verified m89)
#pragma unroll
  for (int mt = 0; mt < MT; ++mt) {
#pragma unroll
    for (int nt = 0; nt < NT; ++nt) {
      int col = wn * (DOUT / 2) + nt * 16 + (lane & 15);
#pragma unroll
      for (int reg = 0; reg < 4; ++reg) {
        int r = wm * 64 + mt * 16 + (lane >> 4) * 4 + reg;
        int d = dst_s[r];
        if (d >= 0) atomicAdd(agg + (size_t)d * DOUT + col, acc[mt][nt][reg]);
      }
    }
  }
}

// out = agg/max(cnt,1) + x@root + bias -> BN -> ReLU
template <int DIN, int DOUT>
__global__ void post_bn(const float* aggv, const float* cnt, const float* xin,
                        const float* root, const float* bias, const float* bg,
                        const float* bb, const float* bm, const float* bv, float* xout) {
  constexpr int TN = 16;             // nodes per block
  constexpr int OSPLIT = 256 / DOUT; // node-groups per block
  __shared__ float xs[TN * DIN];
  int n0 = blockIdx.x * TN;
  int t = threadIdx.x;
  int o = t % DOUT;
  int ng = t / DOUT;
  for (int idx = t; idx < TN * DIN; idx += 256) {
    int nn = idx / DIN, ii = idx % DIN;
    int n = n0 + nn;
    xs[idx] = (n < NN) ? xin[(size_t)n * DIN + ii] : 0.f;
  }
  __syncthreads();
  float scale = bg[o] * rsqrtf(bv[o] + 1e-5f);
  float mo = bm[o], bo = bb[o], bi = bias[o];
  for (int nn = ng; nn < TN; nn += OSPLIT) {
    int n = n0 + nn;
    if (n >= NN) break;
    float a = aggv[(size_t)n * DOUT + o] / fmaxf(cnt[n], 1.f);
    float accv = a + bi;
#pragma unroll 8
    for (int i = 0; i < DIN; ++i) accv += xs[nn * DIN + i] * root[(size_t)i * DOUT + o];
    float v = (accv - mo) * scale + bo;
    xout[(size_t)n * DOUT + o] = v > 0.f ? v : 0.f;
  }
}

__global__ void scan_offsets(const float* gcnt, const int* atom, int* goff, int* gidx) {
  if (threadIdx.x == 0) {
    int off = 0;
    for (int g = 0; g < NG; ++g) {
      goff[g] = off;
      int id = off + atom[g];
      gidx[g] = id < 0 ? 0 : (id > NN - 1 ? NN - 1 : id);  // JAX gather clamp
      off += (int)gcnt[g];
    }
  }
}

__global__ void pool_kernel(const float* x3, const float* gcnt, const int* goff,
                            const int* gidx, float* hnew, float* ne_out) {
  int g = blockIdx.x, o = threadIdx.x;
  int st = goff[g];
  int cn = (int)gcnt[g];
  float s = 0.f;
  for (int n = st; n < st + cn; ++n) s += x3[(size_t)n * 256 + o];
  float ge = s / fmaxf(gcnt[g], 1.f);
  float ne = x3[(size_t)gidx[g] * 256 + o];
  ne_out[g * 256 + o] = ne;                 // node_embedding output
  hnew[g * 256 + o] = 0.5f * ge + ne;
}

__global__ void final_mlp(const float* hnew, const float* mw, const float* mb, float* out) {
  __shared__ float hs[256];
  int g = blockIdx.x, j = threadIdx.x;
  hs[j] = hnew[g * 256 + j];
  __syncthreads();
  if (j < 200) {
    float accv = mb[j];
#pragma unroll 8
    for (int o = 0; o < 256; ++o) accv += hs[o] * mw[(size_t)o * 200 + j];
    out[g * 200 + j] = accv;
  }
}

// ---------------- host side ----------------

template <int DIN, int DOUT, int KTOT, bool POW2>
static void run_layer(void* const* d_in, int l, const float* ea, const int* srcI,
                      const int* dstI, const float* xin, float* xout, float* agg,
                      const float* cnt, float* hedge, short* Bp, short* U,
                      hipStream_t stream) {
  int base = 5 + (l - 1) * 10;
  const float* w1 = (const float*)d_in[base + 0];
  const float* b1 = (const float*)d_in[base + 1];
  const float* w2 = (const float*)d_in[base + 2];
  const float* b2 = (const float*)d_in[base + 3];
  const float* root = (const float*)d_in[base + 4];
  const float* bias = (const float*)d_in[base + 5];
  const float* bg = (const float*)d_in[base + 6];
  const float* bb = (const float*)d_in[base + 7];
  const float* bm = (const float*)d_in[base + 8];
  const float* bv = (const float*)d_in[base + 9];

  edge_mlp<<<(NE + 7) / 8, 256, 0, stream>>>(ea, w1, b1, hedge);
  build_B<DIN, DOUT, KTOT><<<((KTOT / 8) * DOUT + 255) / 256, 256, 0, stream>>>(w2, b2, Bp);
  build_U<DIN, DOUT, KTOT, POW2>
      <<<(NE * (KTOT / 8) + 255) / 256, 256, 0, stream>>>(xin, hedge, srcI, U);
  hipMemsetAsync(agg, 0, (size_t)NN * DOUT * 4, stream);
  gemm_scatter<DIN, DOUT, KTOT>
      <<<dim3(MBLK, KSPLIT), 256, 0, stream>>>(U, Bp, dstI, agg);
  post_bn<DIN, DOUT><<<(NN + 15) / 16, 256, 0, stream>>>(agg, cnt, xin, root, bias, bg,
                                                         bb, bm, bv, xout);
}

extern "C" void kernel_launch(void* const* d_in, const int* in_sizes, int n_in,
                              void* d_out, int out_size, void* d_ws, size_t ws_size,
                              hipStream_t stream) {
  const float* x0 = (const float*)d_in[0];
  const float* ea = (const float*)d_in[1];
  const int* eidx = (const int*)d_in[2];
  const int* batch = (const int*)d_in[3];
  const int* atom = (const int*)d_in[4];
  const float* mw = (const float*)d_in[35];
  const float* mb = (const float*)d_in[36];
  const int* srcI = eidx;
  const int* dstI = eidx + NE;
  float* out = (float*)d_out;

  char* p = (char*)d_ws;
  auto alloc = [&](size_t bytes) {
    char* r = p;
    p += (bytes + 255) & ~size_t(255);
    return r;
  };
  float* xA = (float*)alloc((size_t)NN * 256 * 4);
  float* xB = (float*)alloc((size_t)NN * 256 * 4);
  float* agg = (float*)alloc((size_t)NN * 256 * 4);
  float* cnt = (float*)alloc(NN * 4);
  float* gcnt = (float*)alloc(NG * 4);
  int* goff = (int*)alloc(NG * 4);
  int* gidx = (int*)alloc(NG * 4);
  float* hnew = (float*)alloc((size_t)NG * 256 * 4);
  float* hedge = (float*)alloc((size_t)NE * 32 * 4);
  short* Bp = (short*)alloc((size_t)4224 * 256 * 2);
  short* U = (short*)alloc((size_t)EROWS * 4224 * 2);

  hipMemsetAsync(cnt, 0, NN * 4, stream);
  hipMemsetAsync(gcnt, 0, NG * 4, stream);
  count_edges<<<(NE + 255) / 256, 256, 0, stream>>>(dstI, cnt);
  count_graphs<<<(NN + 255) / 256, 256, 0, stream>>>(batch, gcnt);

  run_layer<15, 64, 512, false>(d_in, 1, ea, srcI, dstI, x0, xA, agg, cnt, hedge, Bp, U, stream);
  run_layer<64, 128, 2112, true>(d_in, 2, ea, srcI, dstI, xA, xB, agg, cnt, hedge, Bp, U, stream);
  run_layer<128, 256, 4224, true>(d_in, 3, ea, srcI, dstI, xB, xA, agg, cnt, hedge, Bp, U, stream);

  scan_offsets<<<1, 64, 0, stream>>>(gcnt, atom, goff, gidx);
  pool_kernel<<<NG, 256, 0, stream>>>(xA, gcnt, goff, gidx, hnew, out + 40000);
  final_mlp<<<NG, 256, 0, stream>>>(hnew, mw, mb, out);
}

// Round 2
// 393.187 us; speedup vs baseline: 1.1057x; 1.1057x over previous
//
#include <hip/hip_runtime.h>
#include <stdint.h>

#define DEVINL __device__ __forceinline__

typedef __attribute__((ext_vector_type(8))) __bf16 bf16x8;
typedef __attribute__((ext_vector_type(8))) short s16x8;
typedef __attribute__((ext_vector_type(4))) float f32x4;

constexpr int NN = 5000;   // nodes
constexpr int NE = 10000;  // edges
constexpr int NG = 200;    // graphs
constexpr int BM = 128;
constexpr int MBLK = (NE + BM - 1) / BM;  // 79
constexpr int KSPLIT = 4;
constexpr int NK = 33;     // 32 edge-MLP k's + 1 bias row (h==1)

DEVINL short f2bf(float f) {  // RNE fp32->bf16
  union { float f; unsigned u; } v; v.f = f;
  unsigned u = v.u + 0x7fffu + ((v.u >> 16) & 1u);
  return (short)(u >> 16);
}

DEVINL float bf2f(unsigned short s) {
  union { unsigned u; float f; } v; v.u = ((unsigned)s) << 16;
  return v.f;
}

DEVINL void gload16(const void* g, void* l) {
  __builtin_amdgcn_global_load_lds(
      (const __attribute__((address_space(1))) void*)g,
      (__attribute__((address_space(3))) void*)l, 16, 0, 0);
}

// ---------------- small kernels ----------------

__global__ void count_edges(const int* dst, float* cnt) {
  int e = blockIdx.x * 256 + threadIdx.x;
  if (e < NE) atomicAdd(&cnt[dst[e]], 1.0f);
}

__global__ void count_graphs(const int* batch, float* gcnt) {
  int n = blockIdx.x * 256 + threadIdx.x;
  if (n < NN) atomicAdd(&gcnt[batch[n]], 1.0f);
}

__global__ void cast_x0(const float* x0, short* xbf0) {
  int idx = blockIdx.x * 256 + threadIdx.x;  // n*32+i
  if (idx >= NN * 32) return;
  int n = idx >> 5, i = idx & 31;
  xbf0[idx] = (i < 15) ? f2bf(x0[n * 15 + i]) : (short)0;
}

// h = relu(edge_attr @ w1 + b1)   [E,3]@[3,32]
__global__ void edge_mlp(const float* ea, const float* w1, const float* b1, float* h) {
  __shared__ float w1s[96];
  __shared__ float b1s[32];
  int t = threadIdx.x;
  if (t < 96) w1s[t] = w1[t];
  if (t < 32) b1s[t] = b1[t];
  __syncthreads();
  int e = blockIdx.x * 8 + (t >> 5);
  int k = t & 31;
  if (e < NE) {
    float a0 = ea[e * 3 + 0], a1 = ea[e * 3 + 1], a2 = ea[e * 3 + 2];
    float v = b1s[k] + a0 * w1s[k] + a1 * w1s[32 + k] + a2 * w1s[64 + k];
    h[e * 32 + k] = v > 0.f ? v : 0.f;
  }
}

// B panel: Bp[kt][n][kk] bf16 (kt = 32-wide K-step), 16B chunks XOR-swizzled
// by ((n>>1)&3).  kap = kt*32+kk = k*DIN_PAD + i;  rows with i>=DIN_DATA are 0.
template <int DIN_DATA, int DIN_PAD, int DOUT>
__global__ void build_B(const float* w2, const float* b2, short* Bp) {
  constexpr int KTOT = NK * DIN_PAD;
  constexpr int TOTC = (KTOT / 8) * DOUT;
  int idx = blockIdx.x * 256 + threadIdx.x;
  if (idx >= TOTC) return;
  int cc = idx & 3;
  int n = (idx >> 2) % DOUT;
  int kt = (idx >> 2) / DOUT;
  int kap0 = kt * 32 + cc * 8;
  s16x8 v;
#pragma unroll
  for (int j = 0; j < 8; ++j) {
    int kap = kap0 + j;
    int k = kap / DIN_PAD, i = kap % DIN_PAD;
    float val = 0.f;
    if (i < DIN_DATA)
      val = (k < 32) ? w2[(size_t)(k * DIN_DATA + i) * DOUT + n]
                     : b2[(size_t)i * DOUT + n];
    v[j] = f2bf(val);
  }
  int swz = cc ^ ((n >> 1) & 3);
  *(s16x8*)((char*)Bp + (size_t)kt * DOUT * 64 + n * 64 + swz * 16) = v;
}

// Fused gather + rank-structured GEMM + atomic scatter.
//   msg[e,o] = sum_k h[e,k] * sum_i xbf[src[e],i] * B[k*DIN_PAD+i, o]
// xg (gathered A) staged ONCE per block (swizzled via per-lane gather source);
// K-loop streams only 32-row B slices (double-buffered, L2-resident).
template <int DIN_PAD, int DOUT>
__launch_bounds__(512, 2)
__global__ void fused_gemm(const short* xbf, const float* hedge, const short* Bp,
                           const int* srcI, const int* dstI, float* agg) {
  constexpr int NI = DIN_PAD / 32;     // K-steps per k
  constexpr int ROWB = DIN_PAD * 2;    // bytes per xg row
  constexpr int CHPR = ROWB / 16;      // 16B chunks per row
  constexpr int CHLOG = (CHPR == 4) ? 2 : (CHPR == 8) ? 3 : 4;
  constexpr int SWZM = (CHPR >= 8) ? 7 : 3;
  constexpr int NT = DOUT / 64;        // 16-col frags per wave (8 waves, 2Mx4N)
  constexpr int MT = 4;                // wave covers 64 rows
  constexpr int PERK = (NK + KSPLIT - 1) / KSPLIT;

  __shared__ __align__(16) short xg[BM * DIN_PAD];
  __shared__ __align__(16) short hs[NK * BM];    // hs[k][r] bf16
  __shared__ __align__(16) char Bb[2][DOUT * 64];
  __shared__ int src_s[BM];
  __shared__ int dst_s[BM];

  const int t = threadIdx.x, lane = t & 63, w = t >> 6;
  const int wm = w >> 2, wn = w & 3;
  const int m0 = blockIdx.x * BM;
  if (t < BM) {
    int e = m0 + t;
    src_s[t] = (e < NE) ? srcI[e] : 0;
    dst_s[t] = (e < NE) ? dstI[e] : -1;
  }
  __syncthreads();

  // gather xg: LDS linear dest, swizzle folded into per-lane global source
  constexpr int XCH = BM * CHPR;
#pragma unroll
  for (int rd = 0; rd < XCH / 512; ++rd) {
    int L = rd * 512 + w * 64 + lane;
    int r = L >> CHLOG, p = L & (CHPR - 1);
    int j = p ^ (r & SWZM);
    gload16((const char*)xbf + (size_t)src_s[r] * ROWB + j * 16,
            (char*)xg + (size_t)(rd * 512 + w * 64) * 16);
  }
  // h transpose-load: hs[k][r] = hedge[m0+r][k] (k=32 -> 1.0 bias row)
  for (int idx = t; idx < NK * BM; idx += 512) {
    int k = idx >> 7, r = idx & 127;
    float v = 1.0f;
    if (k < 32) v = (m0 + r < NE) ? hedge[(m0 + r) * 32 + k] : 0.f;
    hs[k * BM + r] = f2bf(v);
  }
  const int k0 = blockIdx.y * PERK;
  const int k1 = (k0 + PERK < NK) ? (k0 + PERK) : NK;
  const int ktEnd = k1 * NI;
  // stage first B slice into Bb[0]
  const char* Bg = (const char*)Bp;
  {
    int kt = k0 * NI;
#pragma unroll
    for (int cc = 0; cc < (DOUT * 4 + 511) / 512; ++cc) {
      int base = cc * 512 + w * 64;
      if (base < DOUT * 4)
        gload16(Bg + (size_t)kt * (DOUT * 64) + (base + lane) * 16,
                (char*)Bb[0] + base * 16);
    }
  }
  __syncthreads();

  // hoist A fragments (xg is LDS-resident for the whole block)
  bf16x8 afr[NI][MT];
#pragma unroll
  for (int ii = 0; ii < NI; ++ii)
#pragma unroll
    for (int mt = 0; mt < MT; ++mt) {
      int r = wm * 64 + mt * 16 + (lane & 15);
      int c = ii * 4 + (lane >> 4);
      int pos = c ^ (r & SWZM);
      afr[ii][mt] = *(const bf16x8*)((const char*)xg + r * ROWB + pos * 16);
    }

  f32x4 msg[MT][NT], part[MT][NT];
#pragma unroll
  for (int mt = 0; mt < MT; ++mt)
#pragma unroll
    for (int nt = 0; nt < NT; ++nt)
#pragma unroll
      for (int i = 0; i < 4; ++i) { msg[mt][nt][i] = 0.f; part[mt][nt][i] = 0.f; }

  int cur = 0;
  for (int k = k0; k < k1; ++k) {
#pragma unroll
    for (int ii = 0; ii < NI; ++ii) {
      int kt = k * NI + ii;
      if (kt + 1 < ktEnd) {  // prefetch next slice into other buffer
#pragma unroll
        for (int cc = 0; cc < (DOUT * 4 + 511) / 512; ++cc) {
          int base = cc * 512 + w * 64;
          if (base < DOUT * 4)
            gload16(Bg + (size_t)(kt + 1) * (DOUT * 64) + (base + lane) * 16,
                    (char*)Bb[cur ^ 1] + base * 16);
        }
      }
      bf16x8 bfr[NT];
#pragma unroll
      for (int nt = 0; nt < NT; ++nt) {
        int n = wn * (DOUT / 4) + nt * 16 + (lane & 15);
        int cch = (lane >> 4) ^ ((n >> 1) & 3);
        bfr[nt] = *(const bf16x8*)((const char*)Bb[cur] + n * 64 + cch * 16);
      }
#pragma unroll
      for (int mt = 0; mt < MT; ++mt)
#pragma unroll
        for (int nt = 0; nt < NT; ++nt)
          part[mt][nt] = __builtin_amdgcn_mfma_f32_16x16x32_bf16(
              afr[ii][mt], bfr[nt], part[mt][nt], 0, 0, 0);
      if (ii == NI - 1) {  // rescale partial by h[r,k] into msg, reset partial
#pragma unroll
        for (int mt = 0; mt < MT; ++mt) {
          int rb = wm * 64 + mt * 16 + (lane >> 4) * 4;
          ushort4 hv = *(const ushort4*)((const char*)hs + (size_t)(k * BM + rb) * 2);
          float h0 = bf2f(hv.x), h1 = bf2f(hv.y), h2 = bf2f(hv.z), h3 = bf2f(hv.w);
#pragma unroll
          for (int nt = 0; nt < NT; ++nt) {
            msg[mt][nt][0] += h0 * part[mt][nt][0];
            msg[mt][nt][1] += h1 * part[mt][nt][1];
            msg[mt][nt][2] += h2 * part[mt][nt][2];
            msg[mt][nt][3] += h3 * part[mt][nt][3];
#pragma unroll
            for (int i = 0; i < 4; ++i) part[mt][nt][i] = 0.f;
          }
        }
      }
      __syncthreads();
      cur ^= 1;
    }
  }
  // epilogue: C layout col=lane&15, row=(lane>>4)*4+reg (verified)
#pragma unroll
  for (int mt = 0; mt < MT; ++mt)
#pragma unroll
    for (int nt = 0; nt < NT; ++nt) {
      int col = wn * (DOUT / 4) + nt * 16 + (lane & 15);
#pragma unroll
      for (int reg = 0; reg < 4; ++reg) {
        int r = wm * 64 + mt * 16 + (lane >> 4) * 4 + reg;
        int d = dst_s[r];
        if (d >= 0) atomicAdd(agg + (size_t)d * DOUT + col, msg[mt][nt][reg]);
      }
    }
}

// out = agg/max(cnt,1) + x@root + bias -> BN -> ReLU (+ bf16 copy for next layer)
template <int DIN, int DOUT>
__global__ void post_bn(const float* aggv, const float* cnt, const float* xin,
                        const float* root, const float* bias, const float* bg,
                        const float* bb, const float* bm, const float* bv,
                        float* xout, short* xbf) {
  constexpr int TN = 16;
  constexpr int OSPLIT = 256 / DOUT;
  __shared__ float xs[TN * DIN];
  int n0 = blockIdx.x * TN;
  int t = threadIdx.x;
  int o = t % DOUT;
  int ng = t / DOUT;
  for (int idx = t; idx < TN * DIN; idx += 256) {
    int nn = idx / DIN, ii = idx % DIN;
    int n = n0 + nn;
    xs[idx] = (n < NN) ? xin[(size_t)n * DIN + ii] : 0.f;
  }
  __syncthreads();
  float scale = bg[o] * rsqrtf(bv[o] + 1e-5f);
  float mo = bm[o], bo = bb[o], bi = bias[o];
  for (int nn = ng; nn < TN; nn += OSPLIT) {
    int n = n0 + nn;
    if (n >= NN) break;
    float a = aggv[(size_t)n * DOUT + o] / fmaxf(cnt[n], 1.f);
    float accv = a + bi;
#pragma unroll 8
    for (int i = 0; i < DIN; ++i) accv += xs[nn * DIN + i] * root[(size_t)i * DOUT + o];
    float v = (accv - mo) * scale + bo;
    v = v > 0.f ? v : 0.f;
    xout[(size_t)n * DOUT + o] = v;
    if (xbf) xbf[(size_t)n * DOUT + o] = f2bf(v);
  }
}

// parallel exclusive scan of per-graph counts (200 elems, one block)
__global__ void scan_offsets(const float* gcnt, const int* atom, int* goff, int* gidx) {
  __shared__ int s[256];
  int t = threadIdx.x;
  int c = (t < NG) ? (int)gcnt[t] : 0;
  s[t] = c;
  __syncthreads();
  for (int d = 1; d < 256; d <<= 1) {
    int v = (t >= d) ? s[t - d] : 0;
    __syncthreads();
    s[t] += v;
    __syncthreads();
  }
  if (t < NG) {
    int off = s[t] - c;
    goff[t] = off;
    int id = off + atom[t];
    gidx[t] = id < 0 ? 0 : (id > NN - 1 ? NN - 1 : id);  // JAX gather clamp
  }
}

__global__ void pool_kernel(const float* x3, const float* gcnt, const int* goff,
                            const int* gidx, float* hnew, float* ne_out) {
  int g = blockIdx.x, o = threadIdx.x;
  int st = goff[g];
  int cn = (int)gcnt[g];
  float s = 0.f;
  for (int n = st; n < st + cn; ++n) s += x3[(size_t)n * 256 + o];
  float ge = s / fmaxf(gcnt[g], 1.f);
  float ne = x3[(size_t)gidx[g] * 256 + o];
  ne_out[g * 256 + o] = ne;
  hnew[g * 256 + o] = 0.5f * ge + ne;
}

__global__ void final_mlp(const float* hnew, const float* mw, const float* mb, float* out) {
  __shared__ float hs[256];
  int g = blockIdx.x, j = threadIdx.x;
  hs[j] = hnew[g * 256 + j];
  __syncthreads();
  if (j < 200) {
    float accv = mb[j];
#pragma unroll 8
    for (int o = 0; o < 256; ++o) accv += hs[o] * mw[(size_t)o * 200 + j];
    out[g * 200 + j] = accv;
  }
}

// ---------------- host side ----------------

template <int DIN_DATA, int DIN_PAD, int DOUT>
static void run_layer(void* const* d_in, int l, const float* ea, const int* srcI,
                      const int* dstI, const short* xbf_in, const float* xin_f32,
                      float* xout, short* xbf_out, float* agg, const float* cnt,
                      float* hedge, short* Bp, hipStream_t stream) {
  int base = 5 + (l - 1) * 10;
  const float* w1 = (const float*)d_in[base + 0];
  const float* b1 = (const float*)d_in[base + 1];
  const float* w2 = (const float*)d_in[base + 2];
  const float* b2 = (const float*)d_in[base + 3];
  const float* root = (const float*)d_in[base + 4];
  const float* bias = (const float*)d_in[base + 5];
  const float* bg = (const float*)d_in[base + 6];
  const float* bb = (const float*)d_in[base + 7];
  const float* bm = (const float*)d_in[base + 8];
  const float* bv = (const float*)d_in[base + 9];

  edge_mlp<<<(NE + 7) / 8, 256, 0, stream>>>(ea, w1, b1, hedge);
  constexpr int KTOT = NK * DIN_PAD;
  build_B<DIN_DATA, DIN_PAD, DOUT>
      <<<((KTOT / 8) * DOUT + 255) / 256, 256, 0, stream>>>(w2, b2, Bp);
  hipMemsetAsync(agg, 0, (size_t)NN * DOUT * 4, stream);
  fused_gemm<DIN_PAD, DOUT>
      <<<dim3(MBLK, KSPLIT), 512, 0, stream>>>(xbf_in, hedge, Bp, srcI, dstI, agg);
  post_bn<DIN_DATA, DOUT><<<(NN + 15) / 16, 256, 0, stream>>>(
      agg, cnt, xin_f32, root, bias, bg, bb, bm, bv, xout, xbf_out);
}

extern "C" void kernel_launch(void* const* d_in, const int* in_sizes, int n_in,
                              void* d_out, int out_size, void* d_ws, size_t ws_size,
                              hipStream_t stream) {
  const float* x0 = (const float*)d_in[0];
  const float* ea = (const float*)d_in[1];
  const int* eidx = (const int*)d_in[2];
  const int* batch = (const int*)d_in[3];
  const int* atom = (const int*)d_in[4];
  const float* mw = (const float*)d_in[35];
  const float* mb = (const float*)d_in[36];
  const int* srcI = eidx;
  const int* dstI = eidx + NE;
  float* out = (float*)d_out;

  char* p = (char*)d_ws;
  auto alloc = [&](size_t bytes) {
    char* r = p;
    p += (bytes + 255) & ~size_t(255);
    return r;
  };
  float* xA = (float*)alloc((size_t)NN * 256 * 4);
  float* xB = (float*)alloc((size_t)NN * 256 * 4);
  float* agg = (float*)alloc((size_t)NN * 256 * 4);
  float* cnt = (float*)alloc(NN * 4);
  float* gcnt = (float*)alloc(NG * 4);
  int* goff = (int*)alloc(NG * 4);
  int* gidx = (int*)alloc(NG * 4);
  float* hnew = (float*)alloc((size_t)NG * 256 * 4);
  float* hedge = (float*)alloc((size_t)NE * 32 * 4);
  short* Bp = (short*)alloc((size_t)NK * 128 * 256 * 2);  // max KTOT x DOUT bf16
  short* xbf0 = (short*)alloc((size_t)NN * 32 * 2);
  short* xbfA = (short*)alloc((size_t)NN * 64 * 2);
  short* xbfB = (short*)alloc((size_t)NN * 128 * 2);

  hipMemsetAsync(cnt, 0, NN * 4, stream);
  hipMemsetAsync(gcnt, 0, NG * 4, stream);
  count_edges<<<(NE + 255) / 256, 256, 0, stream>>>(dstI, cnt);
  count_graphs<<<(NN + 255) / 256, 256, 0, stream>>>(batch, gcnt);
  cast_x0<<<(NN * 32 + 255) / 256, 256, 0, stream>>>(x0, xbf0);

  run_layer<15, 32, 64>(d_in, 1, ea, srcI, dstI, xbf0, x0, xA, xbfA, agg, cnt,
                        hedge, Bp, stream);
  run_layer<64, 64, 128>(d_in, 2, ea, srcI, dstI, xbfA, xA, xB, xbfB, agg, cnt,
                         hedge, Bp, stream);
  run_layer<128, 128, 256>(d_in, 3, ea, srcI, dstI, xbfB, xB, xA, (short*)nullptr,
                           agg, cnt, hedge, Bp, stream);

  scan_offsets<<<1, 256, 0, stream>>>(gcnt, atom, goff, gidx);
  pool_kernel<<<NG, 256, 0, stream>>>(xA, gcnt, goff, gidx, hnew, out + 40000);
  final_mlp<<<NG, 256, 0, stream>>>(hnew, mw, mb, out);
}